// Round 1
// baseline (1354.673 us; speedup 1.0000x reference)
//
#include <hip/hip_runtime.h>
#include <math.h>

#define NB 32
#define NC 4
#define NH 512
#define NW 512
#define NT 64
#define NG 2

// ---------------------------------------------------------------------------
// Stage 1: diff[b,g,w] = sum_h( ||r0|-|i1|| + ||r1|-|i0|| )
// grid (B*G, 8) x 512 threads; thread = w, block.y = 64-row chunk of H.
// ---------------------------------------------------------------------------
__global__ void k_diff(const float* __restrict__ xr, const float* __restrict__ xi,
                       float* __restrict__ diff) {
  int w  = threadIdx.x;           // 0..511
  int bg = blockIdx.x;            // 0..63  (b*2+g)
  int hc = blockIdx.y;            // 0..7
  int b = bg >> 1, g = bg & 1;
  size_t c0 = ((size_t)(b * NC + 2 * g    )) * NH * NW;
  size_t c1 = ((size_t)(b * NC + 2 * g + 1)) * NH * NW;
  float acc = 0.f;
  int h0 = hc * 64;
  for (int h = h0; h < h0 + 64; ++h) {
    size_t o = (size_t)h * NW + w;
    float r0 = fabsf(xr[c0 + o]);
    float i0 = fabsf(xi[c0 + o]);
    float r1 = fabsf(xr[c1 + o]);
    float i1 = fabsf(xi[c1 + o]);
    acc += fabsf(r0 - i1) + fabsf(r1 - i0);
  }
  atomicAdd(&diff[bg * NW + w], acc);
}

// ---------------------------------------------------------------------------
// Stage 2: select T smallest per (b,g), stable-argsort semantics via rank.
// one block per (b,g), 512 threads.
// ---------------------------------------------------------------------------
__global__ void k_select(const float* __restrict__ diff, int* __restrict__ sel) {
  __shared__ float v[NW];
  int w  = threadIdx.x;
  int bg = blockIdx.x;
  float mine = diff[bg * NW + w];
  v[w] = mine;
  __syncthreads();
  int rank = 0;
  for (int u = 0; u < NW; ++u) {
    float o = v[u];
    rank += (o < mine) || (o == mine && u < w);
  }
  if (rank < NT) sel[bg * NT + rank] = w;   // set of T smallest (order irrelevant)
}

// ---------------------------------------------------------------------------
// Stage 3: Y[img, j, h'] = (1/512) * sum_h x[img, h, w_j] * e^{+2pi i h h'/512}
// one block per (img, j) = 8192 blocks, 512 threads = h'.
// Column + twiddle table staged in LDS; twiddle index incremental (m += t).
// ---------------------------------------------------------------------------
__global__ void k_ifft_h(const float* __restrict__ xr, const float* __restrict__ xi,
                         const int* __restrict__ sel, float2* __restrict__ Y) {
  __shared__ float2 X[NH];
  __shared__ float2 tw[NH];
  int t   = threadIdx.x;          // h'
  int blk = blockIdx.x;
  int j   = blk & (NT - 1);
  int img = blk >> 6;             // b*C + c
  int c = img & 3;
  int b = img >> 2;
  int g = c >> 1;
  int w = sel[(b * NG + g) * NT + j];

  size_t base = (size_t)img * NH * NW + w;
  X[t] = make_float2(xr[base + (size_t)t * NW], xi[base + (size_t)t * NW]);
  float s, cs;
  sincosf(6.2831853071795864769f * (float)t / (float)NH, &s, &cs);
  tw[t] = make_float2(cs, s);     // e^{+2pi i t/512}
  __syncthreads();

  float2 acc = make_float2(0.f, 0.f);
  int m = 0;
#pragma unroll 8
  for (int h = 0; h < NH; ++h) {
    float2 x = X[h];              // broadcast (same addr across lanes)
    float2 e = tw[m];
    acc.x = fmaf(x.x, e.x, acc.x);
    acc.x = fmaf(-x.y, e.y, acc.x);
    acc.y = fmaf(x.x, e.y, acc.y);
    acc.y = fmaf(x.y, e.x, acc.y);
    m = (m + t) & (NH - 1);
  }
  Y[(size_t)blk * NH + t] = make_float2(acc.x * (1.0f / NH), acc.y * (1.0f / NH));
}

// ---------------------------------------------------------------------------
// Stage 4: out[img, h, k] = sum_j Y[img, j, h] * e^{-2pi i k w_j/512} + 0.5
// one block per (img, h) = 65536 blocks, 512 threads = k. Output float2 (re,im).
// ---------------------------------------------------------------------------
__global__ void k_fft_w(const float2* __restrict__ Y, const int* __restrict__ sel,
                        float2* __restrict__ out) {
  __shared__ float2 tw[NW];       // e^{-2pi i m/512}
  __shared__ float2 Yrow[NT];
  __shared__ int    wsel[NT];
  int k   = threadIdx.x;
  int blk = blockIdx.x;           // img*H + h
  int h   = blk & (NH - 1);
  int img = blk >> 9;
  int c = img & 3;
  int b = img >> 2;
  int g = c >> 1;

  float s, cs;
  sincosf(-6.2831853071795864769f * (float)k / (float)NW, &s, &cs);
  tw[k] = make_float2(cs, s);
  if (k < NT) {
    wsel[k] = sel[(b * NG + g) * NT + k];
    Yrow[k] = Y[((size_t)img * NT + k) * NH + h];
  }
  __syncthreads();

  float2 acc = make_float2(0.f, 0.f);
#pragma unroll 8
  for (int j = 0; j < NT; ++j) {
    float2 y = Yrow[j];           // broadcast
    int m = (k * wsel[j]) & (NW - 1);
    float2 e = tw[m];
    acc.x = fmaf(y.x, e.x, acc.x);
    acc.x = fmaf(-y.y, e.y, acc.x);
    acc.y = fmaf(y.x, e.y, acc.y);
    acc.y = fmaf(y.y, e.x, acc.y);
  }
  out[(size_t)blk * NW + k] = make_float2(acc.x + 0.5f, acc.y);
}

extern "C" void kernel_launch(void* const* d_in, const int* in_sizes, int n_in,
                              void* d_out, int out_size, void* d_ws, size_t ws_size,
                              hipStream_t stream) {
  const float* xr = (const float*)d_in[0];
  const float* xi = (const float*)d_in[1];
  float2* out = (float2*)d_out;   // (B,C,H,W,2) -> float2 per (h,k)

  char* ws = (char*)d_ws;
  float* diff = (float*)ws;                         // 64*512*4     = 131072 B
  int*   sel  = (int*)(ws + 131072);                // 64*64*4      = 16384 B
  float2* Y   = (float2*)(ws + 147456);             // 128*64*512*8 = 33.5 MB

  hipMemsetAsync(diff, 0, NB * NG * NW * sizeof(float), stream);
  k_diff  <<<dim3(NB * NG, 8), NW, 0, stream>>>(xr, xi, diff);
  k_select<<<NB * NG,          NW, 0, stream>>>(diff, sel);
  k_ifft_h<<<NB * NC * NT,     NH, 0, stream>>>(xr, xi, sel, Y);
  k_fft_w <<<NB * NC * NH,     NW, 0, stream>>>(Y, sel, out);
}

// Round 2
// 735.754 us; speedup vs baseline: 1.8412x; 1.8412x over previous
//
#include <hip/hip_runtime.h>
#include <math.h>

#define NB 32
#define NC 4
#define NH 512
#define NW 512
#define NT 64
#define NG 2

typedef __attribute__((ext_vector_type(8))) short short8;
typedef __attribute__((ext_vector_type(4))) float float4v;

__device__ inline unsigned short f2bf(float f) {
  union { float f; unsigned u; } v; v.f = f;
  unsigned r = v.u + 0x7FFF + ((v.u >> 16) & 1);
  return (unsigned short)(r >> 16);
}

// ---------------------------------------------------------------------------
// Stage 1: diff[b,g,w] = sum_h( ||r0|-|i1|| + ||r1|-|i0|| )   (fp32, exact)
// ---------------------------------------------------------------------------
__global__ void k_diff(const float* __restrict__ xr, const float* __restrict__ xi,
                       float* __restrict__ diff) {
  int w  = threadIdx.x;
  int bg = blockIdx.x;
  int hc = blockIdx.y;
  int b = bg >> 1, g = bg & 1;
  size_t c0 = ((size_t)(b * NC + 2 * g    )) * NH * NW;
  size_t c1 = ((size_t)(b * NC + 2 * g + 1)) * NH * NW;
  float acc = 0.f;
  int h0 = hc * 64;
  for (int h = h0; h < h0 + 64; ++h) {
    size_t o = (size_t)h * NW + w;
    float r0 = fabsf(xr[c0 + o]);
    float i0 = fabsf(xi[c0 + o]);
    float r1 = fabsf(xr[c1 + o]);
    float i1 = fabsf(xi[c1 + o]);
    acc += fabsf(r0 - i1) + fabsf(r1 - i0);
  }
  atomicAdd(&diff[bg * NW + w], acc);
}

// ---------------------------------------------------------------------------
// Stage 2: T smallest per (b,g), stable-argsort semantics via rank.
// ---------------------------------------------------------------------------
__global__ void k_select(const float* __restrict__ diff, int* __restrict__ sel) {
  __shared__ float v[NW];
  int w  = threadIdx.x;
  int bg = blockIdx.x;
  float mine = diff[bg * NW + w];
  v[w] = mine;
  __syncthreads();
  int rank = 0;
  for (int u = 0; u < NW; ++u) {
    float o = v[u];
    rank += (o < mine) || (o == mine && u < w);
  }
  if (rank < NT) sel[bg * NT + rank] = w;
}

// ---------------------------------------------------------------------------
// Build A_big = [[Tr, -Ti],[Ti, Tr]]  (1024x1024 bf16, row-major [m][k])
// Tr[h',h] = cos(2pi h h'/512)/512 ; Ti = sin(...)/512   (ifft, e^{+i})
// ---------------------------------------------------------------------------
__global__ void k_build_T(unsigned short* __restrict__ Tb) {
  int idx = blockIdx.x * 256 + threadIdx.x;      // 0 .. 1M-1
  int m = idx >> 10, k = idx & 1023;
  int hm = m & 511, rm = m >> 9;
  int hk = k & 511, rk = k >> 9;
  float th = 6.2831853071795864769f * (float)((hm * hk) & 511) * (1.0f / 512.0f);
  float s, c;
  sincosf(th, &s, &c);
  float val;
  if (rm == rk) val = c;                 // Tr
  else if (rk == 1) val = -s;            // -Ti (top-right)
  else val = s;                          // Ti (bottom-left)
  Tb[idx] = f2bf(val * (1.0f / 512.0f));
}

// ---------------------------------------------------------------------------
// Gather selected columns into X_big, layout [n][k]: n = img*64+j (8192 rows),
// k = ri*512 + h (1024).  bf16.
// ---------------------------------------------------------------------------
__global__ void k_gather(const float* __restrict__ xr, const float* __restrict__ xi,
                         const int* __restrict__ sel, unsigned short* __restrict__ Xg) {
  int h = threadIdx.x;                    // 0..511
  int n = blockIdx.x;                     // img*64 + j
  int img = n >> 6, j = n & 63;
  int b = img >> 2, c = img & 3, g = c >> 1;
  int w = sel[(b * NG + g) * NT + j];
  size_t src = (size_t)img * NH * NW + (size_t)h * NW + w;
  Xg[(size_t)n * 1024 + h]       = f2bf(xr[src]);
  Xg[(size_t)n * 1024 + 512 + h] = f2bf(xi[src]);
}

// ---------------------------------------------------------------------------
// Build E_big[bg] layout [n][k]: n in [0,1024) (n<512: real col kk=n, else imag),
// k in [0,128) (k<64: j=k multiplies Yr, else j=k-64 multiplies Yi).
// theta = 2pi kk w_j/512; fft sign e^{-i theta}:
//   real col: [cos | +sin] ; imag col: [-sin | cos]
// ---------------------------------------------------------------------------
__global__ void k_build_E(const int* __restrict__ sel, unsigned short* __restrict__ Eb) {
  __shared__ int wsel[NT];
  int bg = blockIdx.x;
  int tid = threadIdx.x;
  if (tid < NT) wsel[tid] = sel[bg * NT + tid];
  __syncthreads();
  for (int i = 0; i < 512; ++i) {
    int idx = tid + i * 256;               // 0 .. 131071
    int n = idx >> 7, kidx = idx & 127;
    int j = kidx & 63, half = kidx >> 6;
    int part = n >> 9, kk = n & 511;
    int w = wsel[j];
    float th = 6.2831853071795864769f * (float)((kk * w) & 511) * (1.0f / 512.0f);
    float s, c;
    sincosf(th, &s, &c);
    float val;
    if (part == 0) val = (half == 0) ? c : s;
    else           val = (half == 0) ? -s : c;
    Eb[(size_t)bg * 131072 + idx] = f2bf(val);
  }
}

// ---------------------------------------------------------------------------
// GEMM stage 3: C[1024 x 8192] = A_big[1024 x 1024(K)] * X_big
// A layout [m][k]; B layout [n][k]; both bf16. 128x128 block tile, 4 waves,
// each wave 64x64 (4x4 tiles of 16x16x32 MFMA). Epilogue -> Yg bf16
// Yg[img][h][ri*64+j]  (img 128, h 512, 128)
// ---------------------------------------------------------------------------
#define LDK 40

__global__ __launch_bounds__(256) void k_gemm3(const unsigned short* __restrict__ Tb,
                                               const unsigned short* __restrict__ Xg,
                                               unsigned short* __restrict__ Yg) {
  __shared__ __align__(16) unsigned short Al[128 * LDK];
  __shared__ __align__(16) unsigned short Bl[128 * LDK];
  int n0 = blockIdx.x * 128;
  int m0 = blockIdx.y * 128;
  int tid = threadIdx.x;
  int lane = tid & 63, wid = tid >> 6;
  int wm = wid >> 1, wn = wid & 1;
  int quad = lane >> 4, l15 = lane & 15;

  float4v acc[4][4];
#pragma unroll
  for (int i = 0; i < 4; ++i)
#pragma unroll
    for (int j = 0; j < 4; ++j) acc[i][j] = (float4v){0.f, 0.f, 0.f, 0.f};

  for (int k0 = 0; k0 < 1024; k0 += 32) {
    __syncthreads();
#pragma unroll
    for (int p = 0; p < 2; ++p) {
      int r = (tid >> 2) + p * 64;
      int c = (tid & 3) << 3;
      uint4 va = *reinterpret_cast<const uint4*>(&Tb[(size_t)(m0 + r) * 1024 + k0 + c]);
      *reinterpret_cast<uint4*>(&Al[r * LDK + c]) = va;
      uint4 vb = *reinterpret_cast<const uint4*>(&Xg[(size_t)(n0 + r) * 1024 + k0 + c]);
      *reinterpret_cast<uint4*>(&Bl[r * LDK + c]) = vb;
    }
    __syncthreads();

    short8 af[4], bfv[4];
#pragma unroll
    for (int t = 0; t < 4; ++t) {
      af[t]  = *reinterpret_cast<const short8*>(&Al[(wm * 64 + t * 16 + l15) * LDK + quad * 8]);
      bfv[t] = *reinterpret_cast<const short8*>(&Bl[(wn * 64 + t * 16 + l15) * LDK + quad * 8]);
    }
#pragma unroll
    for (int tm = 0; tm < 4; ++tm)
#pragma unroll
      for (int tn = 0; tn < 4; ++tn)
        acc[tm][tn] = __builtin_amdgcn_mfma_f32_16x16x32_bf16(af[tm], bfv[tn], acc[tm][tn], 0, 0, 0);
  }

  // epilogue: C[m,n] -> Yg[(n>>6)][m&511][(m>>9)*64 + (n&63)]
#pragma unroll
  for (int tm = 0; tm < 4; ++tm)
#pragma unroll
    for (int tn = 0; tn < 4; ++tn)
#pragma unroll
      for (int r = 0; r < 4; ++r) {
        int m = m0 + wm * 64 + tm * 16 + quad * 4 + r;
        int n = n0 + wn * 64 + tn * 16 + l15;
        int img = n >> 6, j = n & 63;
        int h = m & 511, ri = m >> 9;
        Yg[((size_t)img * 512 + h) * 128 + ri * 64 + j] = f2bf(acc[tm][tn][r]);
      }
}

// ---------------------------------------------------------------------------
// GEMM stage 4 (batched over bg): C[1024 x 1024] = Yg_bg[1024 x 128(K)] * E_bg
// B LDS rows use paired-column mapping: block covers 64 kk, cols {re,im};
// wave wn covers kk0+wn*32..+32, tiles tn=0,1 real / tn=2,3 imag of same kk.
// Epilogue writes float2 (re+0.5, im) coalesced.
// ---------------------------------------------------------------------------
__global__ __launch_bounds__(256) void k_gemm4(const unsigned short* __restrict__ Yg,
                                               const unsigned short* __restrict__ Eball,
                                               float2* __restrict__ out) {
  __shared__ __align__(16) unsigned short Al[128 * LDK];
  __shared__ __align__(16) unsigned short Bl[128 * LDK];
  int n0 = blockIdx.x * 64;          // kk base (64 kk -> 128 cols)
  int m0 = blockIdx.y * 128;
  int bg = blockIdx.z;
  int b = bg >> 1, g = bg & 1;
  int img0 = b * 4 + 2 * g;
  const unsigned short* Ab = Yg + (size_t)img0 * 512 * 128;
  const unsigned short* Eb = Eball + (size_t)bg * 131072;

  int tid = threadIdx.x;
  int lane = tid & 63, wid = tid >> 6;
  int wm = wid >> 1, wn = wid & 1;
  int quad = lane >> 4, l15 = lane & 15;

  float4v acc[4][4];
#pragma unroll
  for (int i = 0; i < 4; ++i)
#pragma unroll
    for (int j = 0; j < 4; ++j) acc[i][j] = (float4v){0.f, 0.f, 0.f, 0.f};

  for (int k0 = 0; k0 < 128; k0 += 32) {
    __syncthreads();
#pragma unroll
    for (int p = 0; p < 2; ++p) {
      int r = (tid >> 2) + p * 64;
      int c = (tid & 3) << 3;
      uint4 va = *reinterpret_cast<const uint4*>(&Ab[(size_t)(m0 + r) * 128 + k0 + c]);
      *reinterpret_cast<uint4*>(&Al[r * LDK + c]) = va;
      int l = r & 63, wnB = r >> 6;
      int part = l >> 5;
      int grow = part * 512 + n0 + wnB * 32 + (l & 31);
      uint4 vb = *reinterpret_cast<const uint4*>(&Eb[(size_t)grow * 128 + k0 + c]);
      *reinterpret_cast<uint4*>(&Bl[r * LDK + c]) = vb;
    }
    __syncthreads();

    short8 af[4], bfv[4];
#pragma unroll
    for (int t = 0; t < 4; ++t) {
      af[t]  = *reinterpret_cast<const short8*>(&Al[(wm * 64 + t * 16 + l15) * LDK + quad * 8]);
      bfv[t] = *reinterpret_cast<const short8*>(&Bl[(wn * 64 + t * 16 + l15) * LDK + quad * 8]);
    }
#pragma unroll
    for (int tm = 0; tm < 4; ++tm)
#pragma unroll
      for (int tn = 0; tn < 4; ++tn)
        acc[tm][tn] = __builtin_amdgcn_mfma_f32_16x16x32_bf16(af[tm], bfv[tn], acc[tm][tn], 0, 0, 0);
  }

  // epilogue: pair real (tn2) with imag (tn2+2) -> float2 store
#pragma unroll
  for (int tm = 0; tm < 4; ++tm)
#pragma unroll
    for (int t2 = 0; t2 < 2; ++t2)
#pragma unroll
      for (int r = 0; r < 4; ++r) {
        int m = m0 + wm * 64 + tm * 16 + quad * 4 + r;
        int ch = m >> 9, h = m & 511;
        int img = img0 + ch;
        int kk = n0 + wn * 32 + t2 * 16 + l15;
        float2 v = make_float2(acc[tm][t2][r] + 0.5f, acc[tm][t2 + 2][r]);
        out[((size_t)(img * 512 + h)) * 512 + kk] = v;
      }
}

extern "C" void kernel_launch(void* const* d_in, const int* in_sizes, int n_in,
                              void* d_out, int out_size, void* d_ws, size_t ws_size,
                              hipStream_t stream) {
  const float* xr = (const float*)d_in[0];
  const float* xi = (const float*)d_in[1];
  float2* out = (float2*)d_out;

  char* ws = (char*)d_ws;
  float*          diff = (float*)ws;                          // 131072 B
  int*            sel  = (int*)(ws + 131072);                 // 16384 B
  unsigned short* Tb   = (unsigned short*)(ws + 147456);      // 2 MB
  unsigned short* Xg   = (unsigned short*)(ws + 2244608);     // 16 MB
  unsigned short* Yg   = (unsigned short*)(ws + 19021824);    // 16 MB
  unsigned short* Eb   = (unsigned short*)(ws + 35799040);    // 16 MB

  hipMemsetAsync(diff, 0, NB * NG * NW * sizeof(float), stream);
  k_diff   <<<dim3(NB * NG, 8), NW, 0, stream>>>(xr, xi, diff);
  k_select <<<NB * NG,          NW, 0, stream>>>(diff, sel);
  k_build_T<<<4096,             256, 0, stream>>>(Tb);
  k_gather <<<NB * NC * NT,     NH, 0, stream>>>(xr, xi, sel, Xg);
  k_build_E<<<NB * NG,          256, 0, stream>>>(sel, Eb);
  k_gemm3  <<<dim3(64, 8),      256, 0, stream>>>(Tb, Xg, Yg);
  k_gemm4  <<<dim3(8, 8, 64),   256, 0, stream>>>(Yg, Eb, out);
}